// Round 15
// baseline (173.206 us; speedup 1.0000x reference)
//
#include <hip/hip_runtime.h>

#define VQ_D 64
#define VQ_K 512
#define W_FLAG 1.0e-4f

typedef float f32x4 __attribute__((ext_vector_type(4)));
typedef short bf16x8 __attribute__((ext_vector_type(8)));

// f32 -> bf16 RNE (no NaN inputs here)
__device__ __forceinline__ unsigned short f2bf(float f) {
    unsigned u = __float_as_uint(f);
    unsigned r = u + 0x7FFFu + ((u >> 16) & 1u);
    return (unsigned short)(r >> 16);
}
__device__ __forceinline__ float bf2f(unsigned short h) {
    return __uint_as_float(((unsigned)h) << 16);
}

// Monotone float->u32 (negatives below positives) — R4 lesson.
__device__ __forceinline__ unsigned ordkey(float f) {
    const unsigned u = __float_as_uint(f);
    return u ^ (unsigned)(((int)u >> 31) | (int)0x80000000);
}
__device__ __forceinline__ float ordkey_inv(unsigned k) {
    const unsigned u = (k & 0x80000000u) ? (k ^ 0x80000000u) : ~k;
    return __uint_as_float(u);
}

// ---------------------------------------------------------------------------
// numpy pairwise_sum replication for n=64 (proven bit-exact in R2).
// ---------------------------------------------------------------------------
__device__ __forceinline__ float np_sumsq64_g(const float* __restrict__ x)
{
    float r[8];
#pragma unroll
    for (int j = 0; j < 8; ++j) r[j] = __fmul_rn(x[j], x[j]);
#pragma unroll
    for (int i = 8; i < 64; i += 8) {
#pragma unroll
        for (int j = 0; j < 8; ++j)
            r[j] = __fadd_rn(r[j], __fmul_rn(x[i + j], x[i + j]));
    }
    return __fadd_rn(
        __fadd_rn(__fadd_rn(r[0], r[1]), __fadd_rn(r[2], r[3])),
        __fadd_rn(__fadd_rn(r[4], r[5]), __fadd_rn(r[6], r[7])));
}

// ---------------------------------------------------------------------------
// K0: prep (verified R8-R14). Zeroes flag counter AND the f64 loss slot at
// ctr+8 (rescan atomically accumulates flagged-row loss there).
// ---------------------------------------------------------------------------
__global__ __launch_bounds__(256) void vq_prep(
    const float* __restrict__ emb,
    unsigned short* __restrict__ ebh,
    unsigned short* __restrict__ ebl,
    float* __restrict__ s2g,
    float* __restrict__ embT,
    unsigned* __restrict__ ctr)
{
    if (blockIdx.x == 0 && threadIdx.x == 0) {
        ctr[0] = 0u;
        ((double*)ctr)[1] = 0.0;         // flagged-loss slot (ctr+8)
    }

    const int tg = blockIdx.x * 256 + threadIdx.x;   // 0..4095
    const int f  = tg >> 6;                          // fragment 0..63
    const int L  = tg & 63;                          // lane slot
    const int c  = (f >> 1) * 16 + (L & 15);         // code
    const int k0 = (f & 1) * 32 + (L >> 4) * 8;      // k base

    const float* e = emb + (size_t)c * VQ_D + k0;
    const f32x4 v0 = *reinterpret_cast<const f32x4*>(e);
    const f32x4 v1 = *reinterpret_cast<const f32x4*>(e + 4);
    bf16x8 h8, l8;
#pragma unroll
    for (int j = 0; j < 8; ++j) {
        const float fv = (j < 4) ? v0[j] : v1[j - 4];
        const unsigned short h = f2bf(fv);
        h8[j] = (short)h;
        l8[j] = (short)f2bf(__fsub_rn(fv, bf2f(h)));
        embT[(k0 + j) * VQ_K + c] = fv;              // transposed f32 copy
    }
    reinterpret_cast<bf16x8*>(ebh)[f * 64 + L] = h8;
    reinterpret_cast<bf16x8*>(ebl)[f * 64 + L] = l8;

    if (blockIdx.x < 2) {
        const int c2 = blockIdx.x * 256 + threadIdx.x;   // 0..511
        s2g[c2] = np_sumsq64_g(emb + (size_t)c2 * VQ_D);
    }
}

// ---------------------------------------------------------------------------
// K1: SCREEN+EPILOGUE fused (R15). Base = R13/R14-verified LDS-staged screen.
// Change A: epilogue fused — unflagged rows get z_q/idx/loss here (ops
// verbatim from verified K3; rowinfo is wave-synchronous LDS). Flagged rows
// are written entirely by rescan. Kills the separate epilogue kernel, its
// launch gap, the idxflag array, and the 67MB z re-read.
// Change B: 3-chain MFMA split (hh/hl/lh independent accs, combine
// (aH+aM)+aL — exact R7-verified math): chain depth 6 -> 2 for ILP at the
// LDS-capped 2 waves/SIMD. Approx-score rounding shift ~1e-7 << W_FLAG.
// ---------------------------------------------------------------------------
__global__ __launch_bounds__(512) void vq_screen(
    const float* __restrict__ z,
    const float* __restrict__ emb,
    const unsigned short* __restrict__ ebh,
    const unsigned short* __restrict__ ebl,
    const float* __restrict__ s2g,
    float* __restrict__ zq_out,
    float* __restrict__ idx_out,
    unsigned* __restrict__ list,
    unsigned* __restrict__ ctr,
    double* __restrict__ partials)
{
    __shared__ __align__(16) bf16x8 lbh[4096];   // 64 KB
    __shared__ __align__(16) bf16x8 lbl[4096];   // 64 KB
    __shared__ float s2s[VQ_K];
    __shared__ int rowinfo[8 * 32];
    __shared__ double wsum[8];

    const int tid  = threadIdx.x;
    const int wid  = tid >> 6;
    const int lane = tid & 63;
    const int l15  = lane & 15;
    const int kg   = lane >> 4;
    const int rowbase = blockIdx.x * 256 + wid * 32;

    {
        const bf16x8* GH = reinterpret_cast<const bf16x8*>(ebh);
        const bf16x8* GL = reinterpret_cast<const bf16x8*>(ebl);
#pragma unroll
        for (int i = 0; i < 8; ++i) {
            lbh[i * 512 + tid] = GH[i * 512 + tid];
            lbl[i * 512 + tid] = GL[i * 512 + tid];
        }
        if (tid < VQ_K) s2s[tid] = s2g[tid];
    }
    __syncthreads();

    bf16x8 Ah[2][2], Al[2][2];
#pragma unroll
    for (int rg = 0; rg < 2; ++rg) {
#pragma unroll
        for (int kc = 0; kc < 2; ++kc) {
            const float* zp = z + (size_t)(rowbase + rg * 16 + l15) * VQ_D
                            + kc * 32 + kg * 8;
            const f32x4 v0 = *reinterpret_cast<const f32x4*>(zp);
            const f32x4 v1 = *reinterpret_cast<const f32x4*>(zp + 4);
            bf16x8 ah, al;
#pragma unroll
            for (int j = 0; j < 8; ++j) {
                const float fv = (j < 4) ? v0[j] : v1[j - 4];
                const unsigned short h = f2bf(fv);
                ah[j] = (short)h;
                al[j] = (short)f2bf(__fsub_rn(fv, bf2f(h)));
            }
            Ah[rg][kc] = ah; Al[rg][kc] = al;
        }
    }

    float m1[2][4], m2[2][4];
    int   i1[2][4];
#pragma unroll
    for (int rg = 0; rg < 2; ++rg)
#pragma unroll
        for (int j = 0; j < 4; ++j) {
            m1[rg][j] = 3.4e38f; m2[rg][j] = 3.4e38f; i1[rg][j] = 0;
        }

#pragma unroll 4
    for (int t = 0; t < 32; ++t) {
        const bf16x8 Bh0 = lbh[(t * 2 + 0) * 64 + lane];
        const bf16x8 Bl0 = lbl[(t * 2 + 0) * 64 + lane];
        const bf16x8 Bh1 = lbh[(t * 2 + 1) * 64 + lane];
        const bf16x8 Bl1 = lbl[(t * 2 + 1) * 64 + lane];
        const float s2v = s2s[t * 16 + l15];
        const int   cid = t * 16 + l15;
#pragma unroll
        for (int rg = 0; rg < 2; ++rg) {
            // 3 independent 2-deep chains (R7-verified math).
            f32x4 aH = {0.f, 0.f, 0.f, 0.f};
            f32x4 aM = {0.f, 0.f, 0.f, 0.f};
            f32x4 aL = {0.f, 0.f, 0.f, 0.f};
            aH = __builtin_amdgcn_mfma_f32_16x16x32_bf16(Ah[rg][0], Bh0, aH, 0, 0, 0);
            aM = __builtin_amdgcn_mfma_f32_16x16x32_bf16(Ah[rg][0], Bl0, aM, 0, 0, 0);
            aL = __builtin_amdgcn_mfma_f32_16x16x32_bf16(Al[rg][0], Bh0, aL, 0, 0, 0);
            aH = __builtin_amdgcn_mfma_f32_16x16x32_bf16(Ah[rg][1], Bh1, aH, 0, 0, 0);
            aM = __builtin_amdgcn_mfma_f32_16x16x32_bf16(Ah[rg][1], Bl1, aM, 0, 0, 0);
            aL = __builtin_amdgcn_mfma_f32_16x16x32_bf16(Al[rg][1], Bh1, aL, 0, 0, 0);
#pragma unroll
            for (int j = 0; j < 4; ++j) {      // row = kg*4 + j (m89 layout)
                const float tv  = fmaf(-2.0f, (aH[j] + aM[j]) + aL[j], s2v);
                const float o1  = m1[rg][j];
                m1[rg][j] = fminf(o1, tv);
                i1[rg][j] = (tv < o1) ? cid : i1[rg][j];
                m2[rg][j] = fminf(m2[rg][j], fmaxf(tv, o1));
            }
        }
    }

#pragma unroll
    for (int rg = 0; rg < 2; ++rg) {
        unsigned long long k1[4], k2[4];
#pragma unroll
        for (int j = 0; j < 4; ++j) {
            k1[j] = (((unsigned long long)ordkey(m1[rg][j])) << 32) | (unsigned)i1[rg][j];
            k2[j] = (((unsigned long long)ordkey(m2[rg][j])) << 32) | 0x1FFull;
        }
#pragma unroll
        for (int m = 1; m <= 8; m <<= 1) {
#pragma unroll
            for (int j = 0; j < 4; ++j) {
                const unsigned long long o1 = __shfl_xor(k1[j], m, 64);
                const unsigned long long o2 = __shfl_xor(k2[j], m, 64);
                const unsigned long long lo_ = (k1[j] < o1) ? k1[j] : o1;
                const unsigned long long hi_ = (k1[j] < o1) ? o1 : k1[j];
                const unsigned long long s2m = (k2[j] < o2) ? k2[j] : o2;
                k1[j] = lo_;
                k2[j] = (hi_ < s2m) ? hi_ : s2m;
            }
        }
        if (l15 == 0) {
#pragma unroll
            for (int j = 0; j < 4; ++j) {
                const float t1 = ordkey_inv((unsigned)(k1[j] >> 32));
                const float t2 = ordkey_inv((unsigned)(k2[j] >> 32));
                const int idx = (int)(k1[j] & 0x1FFull);
                const int row = rowbase + rg * 16 + kg * 4 + j;
                const int flag = (__fsub_rn(t2, t1) <= W_FLAG) ? 1 : 0;
                rowinfo[wid * 32 + rg * 16 + kg * 4 + j] = idx | (flag << 16);
                if (flag) {
                    const unsigned p = atomicAdd(ctr, 1u);
                    list[p] = (unsigned)row;
                }
            }
        }
    }
    // rowinfo written and read by the same wave -> wave-synchronous, no bar.

    // ---- fused epilogue: UNFLAGGED rows only (ops verbatim from verified
    // K3). 4 lanes/row, 2 passes of 16 rows. Flagged rows: rescan writes.
    double lsum = 0.0;
    {
        const int rr = lane >> 2, seg = lane & 3;
#pragma unroll
        for (int pass = 0; pass < 2; ++pass) {
            const int r = pass * 16 + rr;
            const int info = rowinfo[wid * 32 + r];
            if (!(info >> 16)) {
                const int row = rowbase + r;
                const int idx = info & 0x1FF;
                const float* zp = z + (size_t)row * VQ_D + seg * 16;
                const float* ep = emb + (size_t)idx * VQ_D + seg * 16;
                float* qp = zq_out + (size_t)row * VQ_D + seg * 16;
#pragma unroll
                for (int i = 0; i < 4; ++i) {
                    const f32x4 zv = *reinterpret_cast<const f32x4*>(zp + i * 4);
                    const f32x4 ev = *reinterpret_cast<const f32x4*>(ep + i * 4);
                    f32x4 ov;
#pragma unroll
                    for (int j = 0; j < 4; ++j) {
                        const float d = __fsub_rn(ev[j], zv[j]);
                        ov[j] = __fadd_rn(zv[j], d);
                        lsum += (double)__fmul_rn(d, d);
                    }
                    *reinterpret_cast<f32x4*>(qp + i * 4) = ov;
                }
            }
        }
        if (lane < 32)
            idx_out[rowbase + lane] = (float)(rowinfo[wid * 32 + lane] & 0x1FF);
    }

    // ---- deterministic block loss reduction (unflagged contributions) ----
#pragma unroll
    for (int off = 32; off > 0; off >>= 1)
        lsum += __shfl_down(lsum, off, 64);
    if (lane == 0) wsum[wid] = lsum;
    __syncthreads();
    if (tid == 0) {
        double s = 0.0;
#pragma unroll
        for (int w = 0; w < 8; ++w) s += wsum[w];
        partials[blockIdx.x] = s;
    }
}

// ---------------------------------------------------------------------------
// K2: exact rescan (R14-verified body: one block per flagged row, early
// return, LDS z-row, c = tid) + fused tail: writes idx_out and the z_q row
// (verified STE ops) and atomicAdds its f64 row-loss to lossF (ctr+8).
// ---------------------------------------------------------------------------
__global__ __launch_bounds__(512) void vq_rescan(
    const float* __restrict__ z,
    const float* __restrict__ emb,
    const float* __restrict__ embT,
    const float* __restrict__ s2g,
    const unsigned* __restrict__ list,
    unsigned* __restrict__ ctr,
    float* __restrict__ zq_out,
    float* __restrict__ idx_out)
{
    __shared__ __align__(16) float zs[VQ_D];
    __shared__ unsigned long long wbest[8];
    __shared__ int bidx;
    const int tid  = threadIdx.x;
    const int wid  = tid >> 6;
    const int lane = tid & 63;
    const unsigned count = ctr[0];
    const unsigned i = blockIdx.x;       // one block per flagged row
    if (i >= count) return;

    const int row = (int)list[i];
    if (tid < VQ_D) zs[tid] = z[(size_t)row * VQ_D + tid];
    __syncthreads();

    // Exact numpy pairwise s1 from LDS (verified op order).
    const float s1 = np_sumsq64_g(zs);

    // One code per thread (c = tid); sequential-d fmaf chain (verified).
    const int c = tid;
    float a = 0.f;
#pragma unroll
    for (int d = 0; d < VQ_D; ++d)
        a = fmaf(zs[d], embT[d * VQ_K + c], a);

    const float tv = __fadd_rn(__fsub_rn(s1, __fmul_rn(2.0f, a)), s2g[c]);
    unsigned long long best =
        (((unsigned long long)__float_as_uint(tv)) << 32) | (unsigned)c;
#pragma unroll
    for (int m = 1; m <= 32; m <<= 1) {
        const unsigned long long o = __shfl_xor(best, m, 64);
        best = (o < best) ? o : best;
    }
    if (lane == 0) wbest[wid] = best;
    __syncthreads();
    if (tid == 0) {
        unsigned long long b = wbest[0];
#pragma unroll
        for (int w = 1; w < 8; ++w) b = (wbest[w] < b) ? wbest[w] : b;
        const int bi = (int)(b & 0x1FFull);
        bidx = bi;
        idx_out[row] = (float)bi;
    }
    __syncthreads();

    // Fused epilogue for this flagged row (verified STE/loss ops).
    if (tid < VQ_D) {
        const int idx = bidx;
        const float zv = zs[tid];
        const float ev = emb[(size_t)idx * VQ_D + tid];
        const float d  = __fsub_rn(ev, zv);
        const float ov = __fadd_rn(zv, d);
        zq_out[(size_t)row * VQ_D + tid] = ov;
        double l = (double)__fmul_rn(d, d);
#pragma unroll
        for (int off = 32; off > 0; off >>= 1)
            l += __shfl_down(l, off, 64);
        if (tid == 0)
            atomicAdd((double*)(ctr) + 1, l);   // lossF slot at ctr+8
    }
}

// ---------------------------------------------------------------------------
// K4: finalize (main path): loss = 1.25*(sum(partials) + lossF)/N.
// ---------------------------------------------------------------------------
__global__ __launch_bounds__(256) void vq_finalize2(
    const double* __restrict__ partials, int nparts,
    const unsigned* __restrict__ ctr,
    float* __restrict__ loss_out, double inv_n)
{
    __shared__ double ws[4];
    double s = 0.0;
    for (int i = threadIdx.x; i < nparts; i += 256) s += partials[i];
#pragma unroll
    for (int off = 32; off > 0; off >>= 1)
        s += __shfl_down(s, off, 64);
    const int lane = threadIdx.x & 63, w = threadIdx.x >> 6;
    if (lane == 0) ws[w] = s;
    __syncthreads();
    if (threadIdx.x == 0) {
        const double lossF = ((const double*)ctr)[1];
        loss_out[0] = (float)(1.25 * (ws[0] + ws[1] + ws[2] + ws[3] + lossF) * inv_n);
    }
}

// ---------------------------------------------------------------------------
// K4b: finalize for the fallback path (no lossF).
// ---------------------------------------------------------------------------
__global__ __launch_bounds__(256) void vq_finalize_kernel(
    const double* __restrict__ partials, int nparts,
    float* __restrict__ loss_out, double inv_n)
{
    __shared__ double ws[4];
    double s = 0.0;
    for (int i = threadIdx.x; i < nparts; i += 256) s += partials[i];
#pragma unroll
    for (int off = 32; off > 0; off >>= 1)
        s += __shfl_down(s, off, 64);
    const int lane = threadIdx.x & 63, w = threadIdx.x >> 6;
    if (lane == 0) ws[w] = s;
    __syncthreads();
    if (threadIdx.x == 0)
        loss_out[0] = (float)(1.25 * (ws[0] + ws[1] + ws[2] + ws[3]) * inv_n);
}

// ---------------------------------------------------------------------------
// Fallback (proven R2 kernel) if ws too small.
// ---------------------------------------------------------------------------
__global__ __launch_bounds__(256) void vq_main_kernel(
    const float* __restrict__ z, const float* __restrict__ emb,
    float* __restrict__ zq_out, float* __restrict__ idx_out,
    double* __restrict__ partials, int rows, int use_atomic)
{
    __shared__ float s2[VQ_K];
    __shared__ double wsb[4];
    for (int k = threadIdx.x; k < VQ_K; k += 256)
        s2[k] = np_sumsq64_g(emb + (size_t)k * VQ_D);
    __syncthreads();
    const int row = blockIdx.x * 256 + threadIdx.x;
    double lsum = 0.0;
    if (row < rows) {
        float zr[VQ_D];
        const float* zp = z + (size_t)row * VQ_D;
#pragma unroll
        for (int d = 0; d < VQ_D; d += 4) {
            const float4 v = *reinterpret_cast<const float4*>(zp + d);
            zr[d] = v.x; zr[d+1] = v.y; zr[d+2] = v.z; zr[d+3] = v.w;
        }
        const float s1 = np_sumsq64_g(zr);
        float best = 3.4e38f; int bi = 0;
        for (int k = 0; k < VQ_K; k += 4) {
            const float* e0 = emb + (size_t)(k+0) * VQ_D;
            const float* e1 = emb + (size_t)(k+1) * VQ_D;
            const float* e2 = emb + (size_t)(k+2) * VQ_D;
            const float* e3 = emb + (size_t)(k+3) * VQ_D;
            float a0=0.f,a1=0.f,a2=0.f,a3=0.f;
#pragma unroll
            for (int d = 0; d < VQ_D; ++d) {
                const float zd = zr[d];
                a0 = fmaf(zd, e0[d], a0); a1 = fmaf(zd, e1[d], a1);
                a2 = fmaf(zd, e2[d], a2); a3 = fmaf(zd, e3[d], a3);
            }
            float t;
            t = __fadd_rn(__fsub_rn(s1, __fmul_rn(2.0f, a0)), s2[k+0]);
            if (t < best) { best = t; bi = k+0; }
            t = __fadd_rn(__fsub_rn(s1, __fmul_rn(2.0f, a1)), s2[k+1]);
            if (t < best) { best = t; bi = k+1; }
            t = __fadd_rn(__fsub_rn(s1, __fmul_rn(2.0f, a2)), s2[k+2]);
            if (t < best) { best = t; bi = k+2; }
            t = __fadd_rn(__fsub_rn(s1, __fmul_rn(2.0f, a3)), s2[k+3]);
            if (t < best) { best = t; bi = k+3; }
        }
        const float* eb = emb + (size_t)bi * VQ_D;
        float* zq = zq_out + (size_t)row * VQ_D;
#pragma unroll
        for (int d = 0; d < VQ_D; d += 4) {
            float4 ev, ov;
            ev.x = eb[d]; ev.y = eb[d+1]; ev.z = eb[d+2]; ev.w = eb[d+3];
            const float d0 = __fsub_rn(ev.x, zr[d]);
            const float d1 = __fsub_rn(ev.y, zr[d+1]);
            const float d2 = __fsub_rn(ev.z, zr[d+2]);
            const float d3 = __fsub_rn(ev.w, zr[d+3]);
            ov.x = __fadd_rn(zr[d], d0);   ov.y = __fadd_rn(zr[d+1], d1);
            ov.z = __fadd_rn(zr[d+2], d2); ov.w = __fadd_rn(zr[d+3], d3);
            *reinterpret_cast<float4*>(zq + d) = ov;
            lsum += (double)__fmul_rn(d0,d0) + (double)__fmul_rn(d1,d1)
                  + (double)__fmul_rn(d2,d2) + (double)__fmul_rn(d3,d3);
        }
        idx_out[row] = (float)bi;
    }
#pragma unroll
    for (int off = 32; off > 0; off >>= 1)
        lsum += __shfl_down(lsum, off, 64);
    const int lane = threadIdx.x & 63, w = threadIdx.x >> 6;
    if (lane == 0) wsb[w] = lsum;
    __syncthreads();
    if (threadIdx.x == 0) {
        const double bs = wsb[0] + wsb[1] + wsb[2] + wsb[3];
        if (use_atomic) atomicAdd(partials, bs);
        else partials[blockIdx.x] = bs;
    }
}

extern "C" void kernel_launch(void* const* d_in, const int* in_sizes, int n_in,
                              void* d_out, int out_size, void* d_ws, size_t ws_size,
                              hipStream_t stream) {
    const float* z   = (const float*)d_in[0];
    const float* emb = (const float*)d_in[1];
    float* out = (float*)d_out;

    const int zn   = in_sizes[0];        // 16777216
    const int rows = zn / VQ_D;          // 262144

    float* zq_out   = out;
    float* loss_out = out + zn;
    float* idx_out  = out + zn + 1;

    // ws: ebh 64K | ebl 64K | s2 2K | embT 128K | ctr+lossF 256B | list 1M |
    //     (unused 1M) | partials 32K
    const size_t OFF_EBL  = 65536;
    const size_t OFF_S2   = 131072;
    const size_t OFF_EMBT = 133120;
    const size_t OFF_CTR  = 264192;
    const size_t OFF_LIST = 264448;
    const size_t OFF_IDXF = OFF_LIST + (size_t)rows * 4;   // unused (kept for sizing)
    const size_t OFF_PART = OFF_IDXF + (size_t)rows * 4;
    const int sblocks = rows / 256;      // 1024 screen blocks
    const size_t need = OFF_PART + (size_t)(rows / 64) * sizeof(double);

    if (ws_size >= need && (rows % 256) == 0) {
        unsigned short* ebh = (unsigned short*)d_ws;
        unsigned short* ebl = (unsigned short*)((char*)d_ws + OFF_EBL);
        float* s2g          = (float*)((char*)d_ws + OFF_S2);
        float* embT         = (float*)((char*)d_ws + OFF_EMBT);
        unsigned* ctr       = (unsigned*)((char*)d_ws + OFF_CTR);
        unsigned* list      = (unsigned*)((char*)d_ws + OFF_LIST);
        double* partials    = (double*)((char*)d_ws + OFF_PART);

        vq_prep<<<16, 256, 0, stream>>>(emb, ebh, ebl, s2g, embT, ctr);
        vq_screen<<<sblocks, 512, 0, stream>>>(z, emb, ebh, ebl, s2g,
                                               zq_out, idx_out, list, ctr,
                                               partials);
        vq_rescan<<<8192, 512, 0, stream>>>(z, emb, embT, s2g, list, ctr,
                                            zq_out, idx_out);
        vq_finalize2<<<1, 256, 0, stream>>>(partials, sblocks, ctr,
                                            loss_out, 1.0 / (double)zn);
    } else {
        const int grid = (rows + 255) / 256;
        double* partials = (double*)d_ws;
        const int use_atomic = (ws_size < (size_t)grid * sizeof(double)) ? 1 : 0;
        if (use_atomic) hipMemsetAsync(d_ws, 0, sizeof(double), stream);
        vq_main_kernel<<<grid, 256, 0, stream>>>(z, emb, zq_out, idx_out,
                                                 partials, rows, use_atomic);
        vq_finalize_kernel<<<1, 256, 0, stream>>>(partials, use_atomic ? 1 : grid,
                                                  loss_out, 1.0 / (double)zn);
    }
}

// Round 16
// 152.359 us; speedup vs baseline: 1.1368x; 1.1368x over previous
//
#include <hip/hip_runtime.h>

#define VQ_D 64
#define VQ_K 512
#define W_FLAG 1.0e-4f

typedef float f32x4 __attribute__((ext_vector_type(4)));
typedef short bf16x8 __attribute__((ext_vector_type(8)));

// f32 -> bf16 RNE (no NaN inputs here)
__device__ __forceinline__ unsigned short f2bf(float f) {
    unsigned u = __float_as_uint(f);
    unsigned r = u + 0x7FFFu + ((u >> 16) & 1u);
    return (unsigned short)(r >> 16);
}
__device__ __forceinline__ float bf2f(unsigned short h) {
    return __uint_as_float(((unsigned)h) << 16);
}

// Monotone float->u32 (negatives below positives) — R4 lesson.
__device__ __forceinline__ unsigned ordkey(float f) {
    const unsigned u = __float_as_uint(f);
    return u ^ (unsigned)(((int)u >> 31) | (int)0x80000000);
}
__device__ __forceinline__ float ordkey_inv(unsigned k) {
    const unsigned u = (k & 0x80000000u) ? (k ^ 0x80000000u) : ~k;
    return __uint_as_float(u);
}

// ---------------------------------------------------------------------------
// numpy pairwise_sum replication for n=64 (proven bit-exact in R2).
// ---------------------------------------------------------------------------
__device__ __forceinline__ float np_sumsq64_g(const float* __restrict__ x)
{
    float r[8];
#pragma unroll
    for (int j = 0; j < 8; ++j) r[j] = __fmul_rn(x[j], x[j]);
#pragma unroll
    for (int i = 8; i < 64; i += 8) {
#pragma unroll
        for (int j = 0; j < 8; ++j)
            r[j] = __fadd_rn(r[j], __fmul_rn(x[i + j], x[i + j]));
    }
    return __fadd_rn(
        __fadd_rn(__fadd_rn(r[0], r[1]), __fadd_rn(r[2], r[3])),
        __fadd_rn(__fadd_rn(r[4], r[5]), __fadd_rn(r[6], r[7])));
}

// ---------------------------------------------------------------------------
// K0: prep (verified R8-R14): fragment-major bf16 hi/lo split + transposed
// f32 codebook + exact s2. Zeroes the flagged-row counter.
// ---------------------------------------------------------------------------
__global__ __launch_bounds__(256) void vq_prep(
    const float* __restrict__ emb,
    unsigned short* __restrict__ ebh,
    unsigned short* __restrict__ ebl,
    float* __restrict__ s2g,
    float* __restrict__ embT,
    unsigned* __restrict__ ctr)
{
    if (blockIdx.x == 0 && threadIdx.x == 0) ctr[0] = 0u;

    const int tg = blockIdx.x * 256 + threadIdx.x;   // 0..4095
    const int f  = tg >> 6;                          // fragment 0..63
    const int L  = tg & 63;                          // lane slot
    const int c  = (f >> 1) * 16 + (L & 15);         // code
    const int k0 = (f & 1) * 32 + (L >> 4) * 8;      // k base

    const float* e = emb + (size_t)c * VQ_D + k0;
    const f32x4 v0 = *reinterpret_cast<const f32x4*>(e);
    const f32x4 v1 = *reinterpret_cast<const f32x4*>(e + 4);
    bf16x8 h8, l8;
#pragma unroll
    for (int j = 0; j < 8; ++j) {
        const float fv = (j < 4) ? v0[j] : v1[j - 4];
        const unsigned short h = f2bf(fv);
        h8[j] = (short)h;
        l8[j] = (short)f2bf(__fsub_rn(fv, bf2f(h)));
        embT[(k0 + j) * VQ_K + c] = fv;              // transposed f32 copy
    }
    reinterpret_cast<bf16x8*>(ebh)[f * 64 + L] = h8;
    reinterpret_cast<bf16x8*>(ebl)[f * 64 + L] = l8;

    if (blockIdx.x < 2) {
        const int c2 = blockIdx.x * 256 + threadIdx.x;   // 0..511
        s2g[c2] = np_sumsq64_g(emb + (size_t)c2 * VQ_D);
    }
}

// ---------------------------------------------------------------------------
// K1: SCREEN R16 — code-split waves. Lesson from rescan (R9->R12): time
// tracks PER-WAVE SERIAL CHAIN DEPTH. R12/R14/R15 screens all ran 8192
// waves x 32 serial tiles = one GPU fill, stall-dominated (~890cyc/tile vs
// ~150 issue). Now: block = 128 rows, 8 waves; wave (rq=wid&3, ch=wid>>2)
// owns 32 rows (2 rg, R12-verified fragment path) x HALF the codes (16
// tiles). Serial depth halves, wave count doubles (16384 = 2 fills), no big
// LDS (high occupancy). Halves' top-2 merge via 4KB LDS with the same
// min/max/min formula + packed (t,idx) keys (first-min ties preserved).
// Global-stream B-fragments (R12-verified). 3-chain MFMA split (R7 math).
// ---------------------------------------------------------------------------
__global__ __launch_bounds__(512) void vq_screen(
    const float* __restrict__ z,
    const unsigned short* __restrict__ ebh,
    const unsigned short* __restrict__ ebl,
    const float* __restrict__ s2g,
    int* __restrict__ idxflag,
    unsigned* __restrict__ list,
    unsigned* __restrict__ ctr)
{
    __shared__ float s2s[VQ_K];
    __shared__ unsigned long long topbuf[128][2][2];  // [row][half][k1,k2]

    const int tid  = threadIdx.x;
    const int wid  = tid >> 6;
    const int lane = tid & 63;
    const int l15  = lane & 15;
    const int kg   = lane >> 4;
    const int rq   = wid & 3;            // row quarter (32 rows)
    const int ch   = wid >> 2;           // code half (16 tiles)
    const int rowbase = blockIdx.x * 128 + rq * 32;

    s2s[tid] = s2g[tid];                 // 512 threads cover VQ_K
    __syncthreads();

    // A fragments (R12-verified): row = rg*16+l15, k = kc*32+kg*8+j.
    bf16x8 Ah[2][2], Al[2][2];
#pragma unroll
    for (int rg = 0; rg < 2; ++rg) {
#pragma unroll
        for (int kc = 0; kc < 2; ++kc) {
            const float* zp = z + (size_t)(rowbase + rg * 16 + l15) * VQ_D
                            + kc * 32 + kg * 8;
            const f32x4 v0 = *reinterpret_cast<const f32x4*>(zp);
            const f32x4 v1 = *reinterpret_cast<const f32x4*>(zp + 4);
            bf16x8 ah, al;
#pragma unroll
            for (int j = 0; j < 8; ++j) {
                const float fv = (j < 4) ? v0[j] : v1[j - 4];
                const unsigned short h = f2bf(fv);
                ah[j] = (short)h;
                al[j] = (short)f2bf(__fsub_rn(fv, bf2f(h)));
            }
            Ah[rg][kc] = ah; Al[rg][kc] = al;
        }
    }

    float m1[2][4], m2[2][4];
    int   i1[2][4];
#pragma unroll
    for (int rg = 0; rg < 2; ++rg)
#pragma unroll
        for (int j = 0; j < 4; ++j) {
            m1[rg][j] = 3.4e38f; m2[rg][j] = 3.4e38f; i1[rg][j] = 0;
        }

    const bf16x8* BH = reinterpret_cast<const bf16x8*>(ebh);
    const bf16x8* BL = reinterpret_cast<const bf16x8*>(ebl);

#pragma unroll 2
    for (int tt = 0; tt < 16; ++tt) {
        const int t = ch * 16 + tt;      // this wave's code half
        const bf16x8 Bh0 = BH[(t * 2 + 0) * 64 + lane];
        const bf16x8 Bl0 = BL[(t * 2 + 0) * 64 + lane];
        const bf16x8 Bh1 = BH[(t * 2 + 1) * 64 + lane];
        const bf16x8 Bl1 = BL[(t * 2 + 1) * 64 + lane];
        const float s2v = s2s[t * 16 + l15];
        const int   cid = t * 16 + l15;
#pragma unroll
        for (int rg = 0; rg < 2; ++rg) {
            // 3 independent 2-deep chains (R7-verified math).
            f32x4 aH = {0.f, 0.f, 0.f, 0.f};
            f32x4 aM = {0.f, 0.f, 0.f, 0.f};
            f32x4 aL = {0.f, 0.f, 0.f, 0.f};
            aH = __builtin_amdgcn_mfma_f32_16x16x32_bf16(Ah[rg][0], Bh0, aH, 0, 0, 0);
            aM = __builtin_amdgcn_mfma_f32_16x16x32_bf16(Ah[rg][0], Bl0, aM, 0, 0, 0);
            aL = __builtin_amdgcn_mfma_f32_16x16x32_bf16(Al[rg][0], Bh0, aL, 0, 0, 0);
            aH = __builtin_amdgcn_mfma_f32_16x16x32_bf16(Ah[rg][1], Bh1, aH, 0, 0, 0);
            aM = __builtin_amdgcn_mfma_f32_16x16x32_bf16(Ah[rg][1], Bl1, aM, 0, 0, 0);
            aL = __builtin_amdgcn_mfma_f32_16x16x32_bf16(Al[rg][1], Bh1, aL, 0, 0, 0);
#pragma unroll
            for (int j = 0; j < 4; ++j) {      // row = kg*4 + j (m89 layout)
                const float tv  = fmaf(-2.0f, (aH[j] + aM[j]) + aL[j], s2v);
                const float o1  = m1[rg][j];
                m1[rg][j] = fminf(o1, tv);
                i1[rg][j] = (tv < o1) ? cid : i1[rg][j];
                m2[rg][j] = fminf(m2[rg][j], fmaxf(tv, o1));
            }
        }
    }

    // Wave-internal top-2 merge across the 16 l15 lanes; stash per row+half.
#pragma unroll
    for (int rg = 0; rg < 2; ++rg) {
        unsigned long long k1[4], k2[4];
#pragma unroll
        for (int j = 0; j < 4; ++j) {
            k1[j] = (((unsigned long long)ordkey(m1[rg][j])) << 32) | (unsigned)i1[rg][j];
            k2[j] = (((unsigned long long)ordkey(m2[rg][j])) << 32) | 0x1FFull;
        }
#pragma unroll
        for (int m = 1; m <= 8; m <<= 1) {
#pragma unroll
            for (int j = 0; j < 4; ++j) {
                const unsigned long long o1 = __shfl_xor(k1[j], m, 64);
                const unsigned long long o2 = __shfl_xor(k2[j], m, 64);
                const unsigned long long lo_ = (k1[j] < o1) ? k1[j] : o1;
                const unsigned long long hi_ = (k1[j] < o1) ? o1 : k1[j];
                const unsigned long long s2m = (k2[j] < o2) ? k2[j] : o2;
                k1[j] = lo_;
                k2[j] = (hi_ < s2m) ? hi_ : s2m;
            }
        }
        if (l15 == 0) {
#pragma unroll
            for (int j = 0; j < 4; ++j) {
                const int rb = rq * 32 + rg * 16 + kg * 4 + j;
                topbuf[rb][ch][0] = k1[j];
                topbuf[rb][ch][1] = k2[j];
            }
        }
    }
    __syncthreads();

    // Cross-half merge: one thread per row (128 rows).
    if (tid < 128) {
        const unsigned long long k1a = topbuf[tid][0][0];
        const unsigned long long k2a = topbuf[tid][0][1];
        const unsigned long long k1b = topbuf[tid][1][0];
        const unsigned long long k2b = topbuf[tid][1][1];
        const unsigned long long K1  = (k1a < k1b) ? k1a : k1b;
        const unsigned long long Kx  = (k1a < k1b) ? k1b : k1a;
        const unsigned long long K2m = (k2a < k2b) ? k2a : k2b;
        const unsigned long long K2  = (Kx < K2m) ? Kx : K2m;
        const float t1 = ordkey_inv((unsigned)(K1 >> 32));
        const float t2 = ordkey_inv((unsigned)(K2 >> 32));
        const int idx  = (int)(K1 & 0x1FFull);
        const int row  = blockIdx.x * 128 + tid;
        idxflag[row] = idx;
        if (__fsub_rn(t2, t1) <= W_FLAG) {
            const unsigned p = atomicAdd(ctr, 1u);
            list[p] = (unsigned)row;
        }
    }
}

// ---------------------------------------------------------------------------
// K2: exact rescan (R14-verified, byte-identical): one block per flagged
// row, early return, LDS z-row, np_sumsq64_g on LDS, c = tid.
// ---------------------------------------------------------------------------
__global__ __launch_bounds__(512) void vq_rescan(
    const float* __restrict__ z,
    const float* __restrict__ embT,
    const float* __restrict__ s2g,
    const unsigned* __restrict__ list,
    const unsigned* __restrict__ ctr,
    int* __restrict__ idxflag)
{
    __shared__ __align__(16) float zs[VQ_D];
    __shared__ unsigned long long wbest[8];
    const int tid  = threadIdx.x;
    const int wid  = tid >> 6;
    const int lane = tid & 63;
    const unsigned count = ctr[0];
    const unsigned i = blockIdx.x;       // one block per flagged row
    if (i >= count) return;

    const int row = (int)list[i];
    if (tid < VQ_D) zs[tid] = z[(size_t)row * VQ_D + tid];
    __syncthreads();

    const float s1 = np_sumsq64_g(zs);

    const int c = tid;
    float a = 0.f;
#pragma unroll
    for (int d = 0; d < VQ_D; ++d)
        a = fmaf(zs[d], embT[d * VQ_K + c], a);

    const float tv = __fadd_rn(__fsub_rn(s1, __fmul_rn(2.0f, a)), s2g[c]);
    // tv ~ 64 > 0 always -> raw-bit order fine (proven R2).
    unsigned long long best =
        (((unsigned long long)__float_as_uint(tv)) << 32) | (unsigned)c;
#pragma unroll
    for (int m = 1; m <= 32; m <<= 1) {
        const unsigned long long o = __shfl_xor(best, m, 64);
        best = (o < best) ? o : best;
    }
    if (lane == 0) wbest[wid] = best;
    __syncthreads();
    if (tid == 0) {
        unsigned long long b = wbest[0];
#pragma unroll
        for (int w = 1; w < 8; ++w) b = (wbest[w] < b) ? wbest[w] : b;
        idxflag[row] = (int)(b & 0x1FFull);
    }
}

// ---------------------------------------------------------------------------
// K3: streaming epilogue (R9-R14-verified, byte-identical). 4 lanes/row.
// ---------------------------------------------------------------------------
__global__ __launch_bounds__(256) void vq_epilogue(
    const float* __restrict__ z,
    const float* __restrict__ emb,
    const int* __restrict__ idxflag,
    float* __restrict__ zq_out,
    float* __restrict__ idx_out,
    double* __restrict__ partials)
{
    __shared__ double wsum[4];
    const int tid  = threadIdx.x;
    const int row  = blockIdx.x * 64 + (tid >> 2);
    const int seg  = tid & 3;
    const int idx  = idxflag[row] & 0x1FF;

    const float* zp = z + (size_t)row * VQ_D + seg * 16;
    const float* ep = emb + (size_t)idx * VQ_D + seg * 16;
    float* qp = zq_out + (size_t)row * VQ_D + seg * 16;

    double lsum = 0.0;
#pragma unroll
    for (int i = 0; i < 4; ++i) {
        const f32x4 zv = *reinterpret_cast<const f32x4*>(zp + i * 4);
        const f32x4 ev = *reinterpret_cast<const f32x4*>(ep + i * 4);
        f32x4 ov;
#pragma unroll
        for (int j = 0; j < 4; ++j) {
            const float d = __fsub_rn(ev[j], zv[j]);
            ov[j] = __fadd_rn(zv[j], d);
            lsum += (double)__fmul_rn(d, d);
        }
        *reinterpret_cast<f32x4*>(qp + i * 4) = ov;
    }
    if (seg == 0) idx_out[row] = (float)idx;

#pragma unroll
    for (int off = 32; off > 0; off >>= 1)
        lsum += __shfl_down(lsum, off, 64);
    const int lane = tid & 63, w = tid >> 6;
    if (lane == 0) wsum[w] = lsum;
    __syncthreads();
    if (tid == 0)
        partials[blockIdx.x] = wsum[0] + wsum[1] + wsum[2] + wsum[3];
}

// ---------------------------------------------------------------------------
// K4: reduce partials -> loss = 1.25 * sum / N.
// ---------------------------------------------------------------------------
__global__ __launch_bounds__(256) void vq_finalize_kernel(
    const double* __restrict__ partials, int nparts,
    float* __restrict__ loss_out, double inv_n)
{
    __shared__ double ws[4];
    double s = 0.0;
    for (int i = threadIdx.x; i < nparts; i += 256) s += partials[i];
#pragma unroll
    for (int off = 32; off > 0; off >>= 1)
        s += __shfl_down(s, off, 64);
    const int lane = threadIdx.x & 63, w = threadIdx.x >> 6;
    if (lane == 0) ws[w] = s;
    __syncthreads();
    if (threadIdx.x == 0)
        loss_out[0] = (float)(1.25 * (ws[0] + ws[1] + ws[2] + ws[3]) * inv_n);
}

// ---------------------------------------------------------------------------
// Fallback (proven R2 kernel) if ws too small.
// ---------------------------------------------------------------------------
__global__ __launch_bounds__(256) void vq_main_kernel(
    const float* __restrict__ z, const float* __restrict__ emb,
    float* __restrict__ zq_out, float* __restrict__ idx_out,
    double* __restrict__ partials, int rows, int use_atomic)
{
    __shared__ float s2[VQ_K];
    __shared__ double wsb[4];
    for (int k = threadIdx.x; k < VQ_K; k += 256)
        s2[k] = np_sumsq64_g(emb + (size_t)k * VQ_D);
    __syncthreads();
    const int row = blockIdx.x * 256 + threadIdx.x;
    double lsum = 0.0;
    if (row < rows) {
        float zr[VQ_D];
        const float* zp = z + (size_t)row * VQ_D;
#pragma unroll
        for (int d = 0; d < VQ_D; d += 4) {
            const float4 v = *reinterpret_cast<const float4*>(zp + d);
            zr[d] = v.x; zr[d+1] = v.y; zr[d+2] = v.z; zr[d+3] = v.w;
        }
        const float s1 = np_sumsq64_g(zr);
        float best = 3.4e38f; int bi = 0;
        for (int k = 0; k < VQ_K; k += 4) {
            const float* e0 = emb + (size_t)(k+0) * VQ_D;
            const float* e1 = emb + (size_t)(k+1) * VQ_D;
            const float* e2 = emb + (size_t)(k+2) * VQ_D;
            const float* e3 = emb + (size_t)(k+3) * VQ_D;
            float a0=0.f,a1=0.f,a2=0.f,a3=0.f;
#pragma unroll
            for (int d = 0; d < VQ_D; ++d) {
                const float zd = zr[d];
                a0 = fmaf(zd, e0[d], a0); a1 = fmaf(zd, e1[d], a1);
                a2 = fmaf(zd, e2[d], a2); a3 = fmaf(zd, e3[d], a3);
            }
            float t;
            t = __fadd_rn(__fsub_rn(s1, __fmul_rn(2.0f, a0)), s2[k+0]);
            if (t < best) { best = t; bi = k+0; }
            t = __fadd_rn(__fsub_rn(s1, __fmul_rn(2.0f, a1)), s2[k+1]);
            if (t < best) { best = t; bi = k+1; }
            t = __fadd_rn(__fsub_rn(s1, __fmul_rn(2.0f, a2)), s2[k+2]);
            if (t < best) { best = t; bi = k+2; }
            t = __fadd_rn(__fsub_rn(s1, __fmul_rn(2.0f, a3)), s2[k+3]);
            if (t < best) { best = t; bi = k+3; }
        }
        const float* eb = emb + (size_t)bi * VQ_D;
        float* zq = zq_out + (size_t)row * VQ_D;
#pragma unroll
        for (int d = 0; d < VQ_D; d += 4) {
            float4 ev, ov;
            ev.x = eb[d]; ev.y = eb[d+1]; ev.z = eb[d+2]; ev.w = eb[d+3];
            const float d0 = __fsub_rn(ev.x, zr[d]);
            const float d1 = __fsub_rn(ev.y, zr[d+1]);
            const float d2 = __fsub_rn(ev.z, zr[d+2]);
            const float d3 = __fsub_rn(ev.w, zr[d+3]);
            ov.x = __fadd_rn(zr[d], d0);   ov.y = __fadd_rn(zr[d+1], d1);
            ov.z = __fadd_rn(zr[d+2], d2); ov.w = __fadd_rn(zr[d+3], d3);
            *reinterpret_cast<float4*>(zq + d) = ov;
            lsum += (double)__fmul_rn(d0,d0) + (double)__fmul_rn(d1,d1)
                  + (double)__fmul_rn(d2,d2) + (double)__fmul_rn(d3,d3);
        }
        idx_out[row] = (float)bi;
    }
#pragma unroll
    for (int off = 32; off > 0; off >>= 1)
        lsum += __shfl_down(lsum, off, 64);
    const int lane = threadIdx.x & 63, w = threadIdx.x >> 6;
    if (lane == 0) wsb[w] = lsum;
    __syncthreads();
    if (threadIdx.x == 0) {
        const double bs = wsb[0] + wsb[1] + wsb[2] + wsb[3];
        if (use_atomic) atomicAdd(partials, bs);
        else partials[blockIdx.x] = bs;
    }
}

extern "C" void kernel_launch(void* const* d_in, const int* in_sizes, int n_in,
                              void* d_out, int out_size, void* d_ws, size_t ws_size,
                              hipStream_t stream) {
    const float* z   = (const float*)d_in[0];
    const float* emb = (const float*)d_in[1];
    float* out = (float*)d_out;

    const int zn   = in_sizes[0];        // 16777216
    const int rows = zn / VQ_D;          // 262144

    float* zq_out   = out;
    float* loss_out = out + zn;
    float* idx_out  = out + zn + 1;

    // ws: ebh 64K | ebl 64K | s2 2K | embT 128K | ctr 256B | list 1M |
    //     idxflag 1M | partials 32K
    const size_t OFF_EBL  = 65536;
    const size_t OFF_S2   = 131072;
    const size_t OFF_EMBT = 133120;
    const size_t OFF_CTR  = 264192;
    const size_t OFF_LIST = 264448;
    const size_t OFF_IDXF = OFF_LIST + (size_t)rows * 4;
    const size_t OFF_PART = OFF_IDXF + (size_t)rows * 4;
    const int eblocks = rows / 64;       // 4096 epilogue blocks
    const size_t need = OFF_PART + (size_t)eblocks * sizeof(double);

    if (ws_size >= need && (rows % 128) == 0) {
        unsigned short* ebh = (unsigned short*)d_ws;
        unsigned short* ebl = (unsigned short*)((char*)d_ws + OFF_EBL);
        float* s2g          = (float*)((char*)d_ws + OFF_S2);
        float* embT         = (float*)((char*)d_ws + OFF_EMBT);
        unsigned* ctr       = (unsigned*)((char*)d_ws + OFF_CTR);
        unsigned* list      = (unsigned*)((char*)d_ws + OFF_LIST);
        int* idxflag        = (int*)((char*)d_ws + OFF_IDXF);
        double* partials    = (double*)((char*)d_ws + OFF_PART);

        vq_prep<<<16, 256, 0, stream>>>(emb, ebh, ebl, s2g, embT, ctr);
        vq_screen<<<rows / 128, 512, 0, stream>>>(z, ebh, ebl, s2g,
                                                  idxflag, list, ctr);
        vq_rescan<<<8192, 512, 0, stream>>>(z, embT, s2g, list, ctr, idxflag);
        vq_epilogue<<<eblocks, 256, 0, stream>>>(z, emb, idxflag,
                                                 zq_out, idx_out, partials);
        vq_finalize_kernel<<<1, 256, 0, stream>>>(
            partials, eblocks, loss_out, 1.0 / (double)zn);
    } else {
        const int grid = (rows + 255) / 256;
        double* partials = (double*)d_ws;
        const int use_atomic = (ws_size < (size_t)grid * sizeof(double)) ? 1 : 0;
        if (use_atomic) hipMemsetAsync(d_ws, 0, sizeof(double), stream);
        vq_main_kernel<<<grid, 256, 0, stream>>>(z, emb, zq_out, idx_out,
                                                 partials, rows, use_atomic);
        vq_finalize_kernel<<<1, 256, 0, stream>>>(partials, use_atomic ? 1 : grid,
                                                  loss_out, 1.0 / (double)zn);
    }
}